// Round 10
// baseline (233.050 us; speedup 1.0000x reference)
//
#include <hip/hip_runtime.h>

// LocalSorterModel, collapsed + bf16 MFMA (16x16x32):
//   out[b,r] = sum_x E[b,x] * W[x,r] + const[r],  x = n*1024+d, K=5120
//   WTt[r][x] bf16 from fold GEMM; both GEMMs K-split with fragment-native
//   fp32 partial slices (decode in reduce kernels). 24 KB LDS -> 6 blocks/CU.

#define NR 120
#define KXX 5120
#define PM_SLICE (2048*128)      // floats per main k-split slice  [mtile32][i2][j4][t256][q4]
#define PF_SLICE (128*5120)      // floats per fold k-split slice  [dtile16][n5][i2][j4][t256][q4]

typedef __attribute__((ext_vector_type(8))) short bf8;
typedef __attribute__((ext_vector_type(4))) float f4;

__device__ __forceinline__ unsigned int f2bf(float f) {
    unsigned int x = __builtin_bit_cast(unsigned int, f);
    return (x + 0x7fffu + ((x >> 16) & 1u)) >> 16;
}

// ---- C2R: [640 col][2048 k2] bf16, col = n*128+r (r>=120 zero) ----
__global__ __launch_bounds__(256) void k_prep(const float* __restrict__ cls_w,
                                              unsigned short* __restrict__ C2R) {
    const int col = blockIdx.x, half = blockIdx.y, t = threadIdx.x;
    const int n = col >> 7, r = col & 127;
    unsigned short* dst = C2R + (size_t)col * 2048 + half * 1024 + t * 4;
    if (r >= NR) { *(unsigned long long*)dst = 0ull; return; }
    const float* base = cls_w + (size_t)r * 20480 + t * 4;
    float sx = 0, sy = 0, sz = 0, sw = 0;
    if (half == 0) {
        #pragma unroll
        for (int q = 0; q < 4; q++) {
            float4 v = *(const float4*)(base + (4 * n + q) * 1024);
            sx += v.x; sy += v.y; sz += v.z; sw += v.w;
        }
    } else {
        #pragma unroll
        for (int i = 0; i < 5; i++) {
            if (i == n) continue;
            int q = (n > i) ? (n - 1) : n;
            float4 v = *(const float4*)(base + (4 * i + q) * 1024);
            sx += v.x; sy += v.y; sz += v.z; sw += v.w;
        }
    }
    unsigned long long pk = (unsigned long long)f2bf(sx)
                          | ((unsigned long long)f2bf(sy) << 16)
                          | ((unsigned long long)f2bf(sz) << 32)
                          | ((unsigned long long)f2bf(sw) << 48);
    *(unsigned long long*)dst = pk;
}

// ---- Afold: [1024 d][2048 k2] bf16 = transposed/interleaved pw_w ----
__global__ __launch_bounds__(256) void k_wprep(const float* __restrict__ pw_w,
                                               unsigned short* __restrict__ Afold) {
    __shared__ float T[64][65];
    const int d0 = blockIdx.x * 64, kt0 = blockIdx.y * 64;
    const int h = blockIdx.y >> 4, kr0 = (blockIdx.y & 15) * 64;
    const int t = threadIdx.x;
    #pragma unroll
    for (int lp = 0; lp < 4; lp++) {
        int lk = lp * 16 + (t >> 4);
        float4 v = *(const float4*)(pw_w + (size_t)(kr0 + lk) * 2048 + h * 1024 + d0 + (t & 15) * 4);
        T[lk][(t & 15) * 4 + 0] = v.x; T[lk][(t & 15) * 4 + 1] = v.y;
        T[lk][(t & 15) * 4 + 2] = v.z; T[lk][(t & 15) * 4 + 3] = v.w;
    }
    __syncthreads();
    #pragma unroll
    for (int wp = 0; wp < 2; wp++) {
        int ld = wp * 32 + (t >> 3);
        int lk2 = (t & 7) * 8;
        uint4 o;
        o.x = f2bf(T[lk2 + 0][ld]) | (f2bf(T[lk2 + 1][ld]) << 16);
        o.y = f2bf(T[lk2 + 2][ld]) | (f2bf(T[lk2 + 3][ld]) << 16);
        o.z = f2bf(T[lk2 + 4][ld]) | (f2bf(T[lk2 + 5][ld]) << 16);
        o.w = f2bf(T[lk2 + 6][ld]) | (f2bf(T[lk2 + 7][ld]) << 16);
        *(uint4*)(Afold + (size_t)(d0 + ld) * 2048 + kt0 + lk2) = o;
    }
}

// ---- const[r] = cls_b[r] + sum_k pw_b[k] * sum_{p<20} cls_w[r][p*1024+k] ----
__global__ __launch_bounds__(256) void k_const(const float* __restrict__ cls_w,
                                               const float* __restrict__ pw_b,
                                               const float* __restrict__ cls_b,
                                               float* __restrict__ constv) {
    const int r = blockIdx.x, t = threadIdx.x;
    const float* base = cls_w + (size_t)r * 20480;
    float acc = 0.f;
    for (int k = t; k < 1024; k += 256) {
        float s = 0.f;
        #pragma unroll
        for (int p = 0; p < 20; p++) s += base[p * 1024 + k];
        acc += s * pw_b[k];
    }
    __shared__ float red[256];
    red[t] = acc; __syncthreads();
    for (int s2 = 128; s2 > 0; s2 >>= 1) {
        if (t < s2) red[t] += red[t + s2];
        __syncthreads();
    }
    if (t == 0) constv[r] = cls_b[r] + red[0];
}

// ---- fold GEMM (MFMA): grid(16 d64, 5 n, ksf); native-order fp32 partials ----
__global__ __launch_bounds__(256) void k_fold(const unsigned short* __restrict__ Afold,
                                              const unsigned short* __restrict__ C2R,
                                              float* __restrict__ Pf, int kchunk) {
    __shared__ __align__(16) unsigned short lds[(64 + 128) * 64];   // 24 KB
    unsigned short* Al = lds;
    unsigned short* Bl = lds + 64 * 64;
    const int d0 = blockIdx.x * 64, n = blockIdx.y;
    const int kc0 = blockIdx.z * kchunk;
    const int t = threadIdx.x, lane = t & 63, wv = t >> 6;
    const int wm = wv >> 1, wn = wv & 1;
    const int rr = t >> 3, f = t & 7;

    f4 acc[2][4];
    #pragma unroll
    for (int i = 0; i < 2; i++)
        #pragma unroll
        for (int j = 0; j < 4; j++) acc[i][j] = (f4){0.f, 0.f, 0.f, 0.f};

    const unsigned short* Ag = Afold + (size_t)d0 * 2048 + kc0;
    const unsigned short* Bg = C2R + (size_t)(n * 128) * 2048 + kc0;
    uint4 ra[2], rb[4];
    #pragma unroll
    for (int p = 0; p < 2; p++)
        ra[p] = *(const uint4*)(Ag + (size_t)(p * 32 + rr) * 2048 + f * 8);
    #pragma unroll
    for (int p = 0; p < 4; p++)
        rb[p] = *(const uint4*)(Bg + (size_t)(p * 32 + rr) * 2048 + f * 8);

    const int nst = kchunk >> 6;
    for (int kt = 0; kt < nst; kt++) {
        if (kt) __syncthreads();
        #pragma unroll
        for (int p = 0; p < 2; p++) {
            int row = p * 32 + rr;
            int slot = f ^ (row & 7);
            *(uint4*)(Al + row * 64 + slot * 8) = ra[p];
        }
        #pragma unroll
        for (int p = 0; p < 4; p++) {
            int row = p * 32 + rr;
            int slot = f ^ (row & 7);
            *(uint4*)(Bl + row * 64 + slot * 8) = rb[p];
        }
        __syncthreads();
        if (kt + 1 < nst) {
            int kb = (kt + 1) * 64;
            #pragma unroll
            for (int p = 0; p < 2; p++)
                ra[p] = *(const uint4*)(Ag + (size_t)(p * 32 + rr) * 2048 + kb + f * 8);
            #pragma unroll
            for (int p = 0; p < 4; p++)
                rb[p] = *(const uint4*)(Bg + (size_t)(p * 32 + rr) * 2048 + kb + f * 8);
        }
        #pragma unroll
        for (int s = 0; s < 2; s++) {
            bf8 af[2], bq[4];
            #pragma unroll
            for (int ff = 0; ff < 2; ff++) {
                int rowa = wm * 32 + ff * 16 + (lane & 15);
                int sla = (s * 4 + (lane >> 4)) ^ (rowa & 7);
                af[ff] = *reinterpret_cast<const bf8*>(Al + rowa * 64 + sla * 8);
            }
            #pragma unroll
            for (int ff = 0; ff < 4; ff++) {
                int rowb = wn * 64 + ff * 16 + (lane & 15);
                int slb = (s * 4 + (lane >> 4)) ^ (rowb & 7);
                bq[ff] = *reinterpret_cast<const bf8*>(Bl + rowb * 64 + slb * 8);
            }
            #pragma unroll
            for (int i = 0; i < 2; i++)
                #pragma unroll
                for (int j = 0; j < 4; j++)
                    acc[i][j] = __builtin_amdgcn_mfma_f32_16x16x32_bf16(af[i], bq[j], acc[i][j], 0, 0, 0);
        }
    }
    // fragment-native coalesced store: slice [dtile][n][i][j][t][q]
    float* dst = Pf + (size_t)blockIdx.z * PF_SLICE
               + ((size_t)(blockIdx.x * 5 + n)) * 8192;
    #pragma unroll
    for (int i = 0; i < 2; i++)
        #pragma unroll
        for (int j = 0; j < 4; j++)
            *(f4*)(dst + (((i * 4 + j) * 256 + t) * 4)) = acc[i][j];
}

// ---- fold reduce + decode: WTt[r][x] bf16 = sum_ks Pf[ks][frag(r,x)] ----
__global__ __launch_bounds__(256) void k_foldred(const float* __restrict__ Pf,
                                                 unsigned short* __restrict__ WTt,
                                                 int ksf) {
    int tid = blockIdx.x * 256 + threadIdx.x;      // 128 * 1280
    int r = tid / 1280, x4 = tid - r * 1280;
    int n = x4 >> 8;
    int dtile = (x4 & 255) >> 4;
    int wm = (x4 & 15) >> 3;
    int i = (x4 >> 2) & 1;
    int lanehi = x4 & 3;
    int wn = r >> 6, j = (r >> 4) & 3, lanelo = r & 15;
    int tsrc = (wm * 2 + wn) * 64 + lanehi * 16 + lanelo;
    size_t idx = ((((size_t)(dtile * 5 + n) * 2 + i) * 4 + j) * 256 + tsrc) * 4;
    float4 s = *(const float4*)(Pf + idx);
    for (int ks = 1; ks < ksf; ks++) {
        float4 v = *(const float4*)(Pf + (size_t)ks * PF_SLICE + idx);
        s.x += v.x; s.y += v.y; s.z += v.z; s.w += v.w;
    }
    unsigned long long pk = (unsigned long long)f2bf(s.x)
                          | ((unsigned long long)f2bf(s.y) << 16)
                          | ((unsigned long long)f2bf(s.z) << 32)
                          | ((unsigned long long)f2bf(s.w) << 48);
    *(unsigned long long*)(WTt + (size_t)r * KXX + x4 * 4) = pk;
}

// ---- main GEMM (MFMA): 64b x 128r tiles, grid(32, nksm); native-order Pm ----
__global__ __launch_bounds__(256) void k_main(const float* __restrict__ E,
                                              const unsigned short* __restrict__ WTt,
                                              float* __restrict__ Pm, int kchunk) {
    __shared__ __align__(16) unsigned short lds[(64 + 128) * 64];   // 24 KB
    unsigned short* Al = lds;
    unsigned short* Bl = lds + 64 * 64;
    const int m0 = blockIdx.x * 64;
    const int kc0 = blockIdx.y * kchunk;
    const int t = threadIdx.x, lane = t & 63, wv = t >> 6;
    const int wm = wv >> 1, wn = wv & 1;
    const int rrb = t >> 3, f = t & 7;     // B staging
    const int rra = t >> 2, fa = t & 3;    // A staging

    f4 acc[2][4];
    #pragma unroll
    for (int i = 0; i < 2; i++)
        #pragma unroll
        for (int j = 0; j < 4; j++) acc[i][j] = (f4){0.f, 0.f, 0.f, 0.f};

    const float* Ag = E + (size_t)m0 * KXX + kc0;
    const unsigned short* Bg = WTt + kc0;
    float4 raA[2][4];
    uint4 raB[2][4];
    const int nst = kchunk >> 6;
    #pragma unroll
    for (int st = 0; st < 2; st++) {
        int kb = st * 64;
        #pragma unroll
        for (int u = 0; u < 4; u++)
            raA[st][u] = *(const float4*)(Ag + (size_t)rra * KXX + kb + fa * 16 + u * 4);
        #pragma unroll
        for (int p = 0; p < 4; p++)
            raB[st][p] = *(const uint4*)(Bg + (size_t)(p * 32 + rrb) * KXX + kb + f * 8);
    }
    for (int kt = 0; kt < nst; kt++) {
        const int par = kt & 1;
        if (kt) __syncthreads();
        #pragma unroll
        for (int u = 0; u < 2; u++) {
            float4 v0 = raA[par][2 * u], v1 = raA[par][2 * u + 1];
            uint4 o;
            o.x = f2bf(v0.x) | (f2bf(v0.y) << 16);
            o.y = f2bf(v0.z) | (f2bf(v0.w) << 16);
            o.z = f2bf(v1.x) | (f2bf(v1.y) << 16);
            o.w = f2bf(v1.z) | (f2bf(v1.w) << 16);
            int slot = (fa * 2 + u) ^ (rra & 7);
            *(uint4*)(Al + rra * 64 + slot * 8) = o;
        }
        #pragma unroll
        for (int p = 0; p < 4; p++) {
            int row = p * 32 + rrb;
            int slot = f ^ (row & 7);
            *(uint4*)(Bl + row * 64 + slot * 8) = raB[par][p];
        }
        __syncthreads();
        if (kt + 2 < nst) {
            int kb = (kt + 2) * 64;
            #pragma unroll
            for (int u = 0; u < 4; u++)
                raA[par][u] = *(const float4*)(Ag + (size_t)rra * KXX + kb + fa * 16 + u * 4);
            #pragma unroll
            for (int p = 0; p < 4; p++)
                raB[par][p] = *(const uint4*)(Bg + (size_t)(p * 32 + rrb) * KXX + kb + f * 8);
        }
        #pragma unroll
        for (int s = 0; s < 2; s++) {
            bf8 af[2], bq[4];
            #pragma unroll
            for (int ff = 0; ff < 2; ff++) {
                int rowa = wm * 32 + ff * 16 + (lane & 15);
                int sla = (s * 4 + (lane >> 4)) ^ (rowa & 7);
                af[ff] = *reinterpret_cast<const bf8*>(Al + rowa * 64 + sla * 8);
            }
            #pragma unroll
            for (int ff = 0; ff < 4; ff++) {
                int rowb = wn * 64 + ff * 16 + (lane & 15);
                int slb = (s * 4 + (lane >> 4)) ^ (rowb & 7);
                bq[ff] = *reinterpret_cast<const bf8*>(Bl + rowb * 64 + slb * 8);
            }
            #pragma unroll
            for (int i = 0; i < 2; i++)
                #pragma unroll
                for (int j = 0; j < 4; j++)
                    acc[i][j] = __builtin_amdgcn_mfma_f32_16x16x32_bf16(af[i], bq[j], acc[i][j], 0, 0, 0);
        }
    }
    // fragment-native coalesced store: slice [mtile][i][j][t][q]
    float* dst = Pm + (size_t)blockIdx.y * PM_SLICE + (size_t)blockIdx.x * 8192;
    #pragma unroll
    for (int i = 0; i < 2; i++)
        #pragma unroll
        for (int j = 0; j < 4; j++)
            *(f4*)(dst + (((i * 4 + j) * 256 + t) * 4)) = acc[i][j];
}

// ---- main reduce + decode: out[b][r] = const[r] + sum_ks Pm[ks][frag(b,r)] ----
__global__ __launch_bounds__(256) void k_mainred(const float* __restrict__ Pm,
                                                 const float* __restrict__ constv,
                                                 float* __restrict__ out, int nksm) {
    int tid = blockIdx.x * 256 + threadIdx.x;      // 512 * 120
    int b4 = tid / NR, r = tid - b4 * NR;
    int mtile = b4 >> 4;
    int wm = (b4 & 15) >> 3;
    int i = (b4 >> 2) & 1;
    int lanehi = b4 & 3;
    int wn = r >> 6, j = (r >> 4) & 3, lanelo = r & 15;
    int tsrc = (wm * 2 + wn) * 64 + lanehi * 16 + lanelo;
    size_t idx = (((size_t)(mtile * 2 + i) * 4 + j) * 256 + tsrc) * 4;
    float4 s = *(const float4*)(Pm + idx);
    for (int ks = 1; ks < nksm; ks++) {
        float4 v = *(const float4*)(Pm + (size_t)ks * PM_SLICE + idx);
        s.x += v.x; s.y += v.y; s.z += v.z; s.w += v.w;
    }
    float c = constv[r];
    int b = b4 * 4;
    out[(size_t)(b + 0) * NR + r] = s.x + c;
    out[(size_t)(b + 1) * NR + r] = s.y + c;
    out[(size_t)(b + 2) * NR + r] = s.z + c;
    out[(size_t)(b + 3) * NR + r] = s.w + c;
}

extern "C" void kernel_launch(void* const* d_in, const int* in_sizes, int n_in,
                              void* d_out, int out_size, void* d_ws, size_t ws_size,
                              hipStream_t stream) {
    const float* embeds = (const float*)d_in[0];
    const float* pw_w   = (const float*)d_in[1];
    const float* pw_b   = (const float*)d_in[2];
    const float* cls_w  = (const float*)d_in[3];
    const float* cls_b  = (const float*)d_in[4];
    float* out = (float*)d_out;

    unsigned short* C2R   = (unsigned short*)d_ws;          // 640*2048 bf16
    unsigned short* Afold = C2R + (size_t)640 * 2048;       // 1024*2048 bf16
    unsigned short* WTt   = Afold + (size_t)1024 * 2048;    // 128*5120 bf16
    float* constv = (float*)(WTt + (size_t)128 * 5120);     // 128 f32
    float* scratch = constv + 128;                          // Pf, then Pm (aliased)

    size_t base = ((size_t)640 * 2048 + (size_t)1024 * 2048 + (size_t)128 * 5120) * 2 + 512;
    size_t avail = (ws_size > base) ? (ws_size - base) / 4 : 0;
    const int candm[9] = {40, 20, 16, 10, 8, 5, 4, 2, 1};   // divisors of 80
    int nksm = 1;
    for (int ci = 0; ci < 9; ci++)
        if ((size_t)candm[ci] * PM_SLICE <= avail) { nksm = candm[ci]; break; }
    const int candf[5] = {16, 8, 4, 2, 1};                  // divisors of 32
    int ksf = 1;
    for (int ci = 0; ci < 5; ci++)
        if ((size_t)candf[ci] * PF_SLICE <= avail) { ksf = candf[ci]; break; }

    k_const<<<dim3(NR), dim3(256), 0, stream>>>(cls_w, pw_b, cls_b, constv);
    k_prep<<<dim3(640, 2), dim3(256), 0, stream>>>(cls_w, C2R);
    k_wprep<<<dim3(16, 32), dim3(256), 0, stream>>>(pw_w, Afold);
    k_fold<<<dim3(16, 5, ksf), dim3(256), 0, stream>>>(Afold, C2R, scratch, 2048 / ksf);
    k_foldred<<<dim3(640), dim3(256), 0, stream>>>(scratch, WTt, ksf);
    k_main<<<dim3(32, nksm), dim3(256), 0, stream>>>(embeds, WTt, scratch, KXX / nksm);
    k_mainred<<<dim3(240), dim3(256), 0, stream>>>(scratch, constv, out, nksm);
}